// Round 3
// baseline (195.614 us; speedup 1.0000x reference)
//
#include <hip/hip_runtime.h>
#include <hip/hip_bf16.h>
#include <hip/hip_cooperative_groups.h>
#include <math.h>

namespace cg = cooperative_groups;

#define B_DIM 16
#define T_DIM 100
#define TPAD 112            // 7 MFMA row-tiles of 16
#define HW_PIX (27 * 48)    // 1296 pixels/frame
#define NBINS 512
#define WIN 101
#define HALF 50
#define ODIM 128
#define NTILE 7             // TPAD/16
#define SSTRIDE 132         // S-block row stride in LDS (132%32=4 -> only 2-way aliasing)
#define NBLOCKS 512         // 2 blocks/CU co-resident (60160B LDS each) -> cooperative-valid
#define NFRAMES (B_DIM * T_DIM)

typedef __attribute__((ext_vector_type(8))) short s16x8;
typedef __attribute__((ext_vector_type(4))) float f32x4;

// ---------------------------------------------------------------------------
// Single fused cooperative kernel.
//
// LDS map (60160 B total, static):
//   [0      .. 51712) : phase 1 = 4 per-wave histograms (4 x 512 int = 8 KB)
//                       phase 2 = fc_w staged as f32 (101x128 = 51712 B)
//   [51712  .. 60160) : slds S-block (16 x 132 f32)
//
// Phase H (all 512 blocks): wave-per-frame histogram.
//   gwave = bid*4+wv in [0,2048): waves 0..1599 own one frame each,
//   waves 1600..1615 zero row 100 of batch (gwave-1600) — the clamp row for
//   out-of-range band columns. Wave-private hist -> no barriers, no
//   cross-wave atomic contention, perfect balance.
// grid.sync()
// Phase S (blocks 0..111): sim via MFMA + band + FC(101->128) + ReLU,
//   identical math to the previous 2-kernel version.
// ---------------------------------------------------------------------------
__global__ __launch_bounds__(256, 2) void fused_kernel(
    const int* __restrict__ frames, const float* __restrict__ fc_w,
    const float* __restrict__ fc_b, float* __restrict__ out,
    __hip_bfloat16* __restrict__ X16) {
  __shared__ __align__(16) unsigned char smem[WIN * ODIM * 4 + 16 * SSTRIDE * 4];
  float* wlds = (float*)smem;                      // 51712 B
  float* slds = (float*)(smem + WIN * ODIM * 4);   // 8448 B

  const int bid = blockIdx.x;
  const int tid = threadIdx.x;
  const int lane = tid & 63, wv = tid >> 6;

  // ---- Phase H: wave-per-frame histogram ----
  {
    int* hw = (int*)smem + wv * NBINS;             // wave-private 2 KB
    const int gwave = bid * 4 + wv;

    if (gwave < NFRAMES) {
#pragma unroll
      for (int k = 0; k < 8; ++k) hw[lane + 64 * k] = 0;

      // 324 groups of 4 pixels (12 dwords = 3 int4 loads each)
      const int* fp = frames + (size_t)gwave * (HW_PIX * 3);
      for (int g = lane; g < HW_PIX / 4; g += 64) {
        const int4* q = (const int4*)(fp + 12 * g);
        int4 a = q[0], c = q[1], e = q[2];
        int b0 = ((a.x >> 5) << 6) + ((a.y >> 5) << 3) + (a.z >> 5);
        int b1 = ((a.w >> 5) << 6) + ((c.x >> 5) << 3) + (c.y >> 5);
        int b2 = ((c.z >> 5) << 6) + ((c.w >> 5) << 3) + (e.x >> 5);
        int b3 = ((e.y >> 5) << 6) + ((e.z >> 5) << 3) + (e.w >> 5);
        atomicAdd(&hw[b0], 1);
        atomicAdd(&hw[b1], 1);
        atomicAdd(&hw[b2], 1);
        atomicAdd(&hw[b3], 1);
      }

      // L2-norm: partition bins as lane+64k (conflict-free)
      float ss = 0.f;
#pragma unroll
      for (int k = 0; k < 8; ++k) {
        float v = (float)hw[lane + 64 * k];
        ss += v * v;
      }
#pragma unroll
      for (int off = 32; off > 0; off >>= 1) ss += __shfl_xor(ss, off);
      const float rn = 1.0f / sqrtf(ss);

      // packed bf16 store: dword i <- bins {2i, 2i+1}, i = lane+64k
      const int b = gwave / T_DIM;
      const int t = gwave - b * T_DIM;
      unsigned int* row = (unsigned int*)(X16 + ((size_t)(b * TPAD + t)) * NBINS);
      const int2* h2 = (const int2*)hw;
#pragma unroll
      for (int k = 0; k < 4; ++k) {
        int i = lane + 64 * k;
        int2 p = h2[i];
        unsigned int lo = (unsigned int)__bfloat16_as_ushort(
            __float2bfloat16((float)p.x * rn));
        unsigned int hi = (unsigned int)__bfloat16_as_ushort(
            __float2bfloat16((float)p.y * rn));
        row[i] = lo | (hi << 16);
      }
    } else if (gwave < NFRAMES + B_DIM) {
      // zero row 100 of batch (gwave-1600): clamp target for OOB band cols
      const int b = gwave - NFRAMES;
      unsigned int* zr = (unsigned int*)(X16 + ((size_t)(b * TPAD + T_DIM)) * NBINS);
#pragma unroll
      for (int k = 0; k < 4; ++k) zr[lane + 64 * k] = 0u;
    }
  }

  __syncthreads();   // all waves done with hist scratch (aliases wlds)

  const bool worker = (bid < B_DIM * NTILE);

  // stage fc_w now: input-only dependency -> overlaps the grid-sync wait
  if (worker) {
    const f32x4* src = (const f32x4*)fc_w;
    f32x4* dst = (f32x4*)wlds;
    for (int i = tid; i < (WIN * ODIM) / 4; i += 256) dst[i] = src[i];
  }

  __threadfence();            // make X16 stores device-visible (belt & braces)
  cg::this_grid().sync();     // X16 complete everywhere

  if (!worker) return;

  // ---- Phase S: MFMA S-block ----
  const int b = bid / NTILE;
  const int t0 = (bid - b * NTILE) * 16;
  const int m16 = lane & 15, quad = lane >> 4;

  // A rows t0+m16 <= 111 < TPAD (pad rows 101..111 feed only discarded
  // outputs; row 100 is zeroed).
  const short* Abase =
      (const short*)(X16 + ((size_t)(b * TPAD + t0 + m16)) * NBINS) + quad * 8;
  const short* zrow =
      (const short*)(X16 + ((size_t)(b * TPAD + T_DIM)) * NBINS) + quad * 8;

  // wave wv owns columns n in [wv*32, wv*32+31] (two 16-wide n-tiles)
  const int s0 = t0 - HALF + wv * 32 + m16;
  const int s1 = s0 + 16;
  const short* B0 = (s0 >= 0 && s0 < T_DIM)
      ? (const short*)(X16 + ((size_t)(b * TPAD + s0)) * NBINS) + quad * 8
      : zrow;
  const short* B1 = (s1 >= 0 && s1 < T_DIM)
      ? (const short*)(X16 + ((size_t)(b * TPAD + s1)) * NBINS) + quad * 8
      : zrow;

  f32x4 acc0 = {0.f, 0.f, 0.f, 0.f};
  f32x4 acc1 = {0.f, 0.f, 0.f, 0.f};
#pragma unroll 8
  for (int k = 0; k < NBINS; k += 32) {
    s16x8 af = *(const s16x8*)(Abase + k);
    s16x8 bf0 = *(const s16x8*)(B0 + k);
    s16x8 bf1 = *(const s16x8*)(B1 + k);
    acc0 = __builtin_amdgcn_mfma_f32_16x16x32_bf16(af, bf0, acc0, 0, 0, 0);
    acc1 = __builtin_amdgcn_mfma_f32_16x16x32_bf16(af, bf1, acc1, 0, 0, 0);
  }

  // D layout: col = lane&15, row = quad*4 + r. Stride 132 -> 2-way max (free).
#pragma unroll
  for (int r = 0; r < 4; ++r) {
    slds[(quad * 4 + r) * SSTRIDE + wv * 32 + m16] = acc0[r];
    slds[(quad * 4 + r) * SSTRIDE + wv * 32 + 16 + m16] = acc1[r];
  }
  __syncthreads();

  // ---- FC: band[tl][j] = S[tl][tl+j] (max col 15+100=115 < 128) ----
  const int g4 = tid & 31;        // d = 4*g4 .. 4*g4+3
  const int tl0 = tid >> 5;       // 0..7
  const int tl1 = tl0 + 8;

  f32x4 accA = ((const f32x4*)fc_b)[g4];
  f32x4 accB = accA;
#pragma unroll 4
  for (int j = 0; j < WIN; ++j) {
    f32x4 w4 = *(const f32x4*)&wlds[j * ODIM + g4 * 4];
    float v0 = slds[tl0 * SSTRIDE + tl0 + j];
    float v1 = slds[tl1 * SSTRIDE + tl1 + j];
    accA += w4 * v0;
    accB += w4 * v1;
  }

#pragma unroll
  for (int c = 0; c < 4; ++c) {
    accA[c] = fmaxf(accA[c], 0.f);
    accB[c] = fmaxf(accB[c], 0.f);
  }

  const int ta = t0 + tl0, tb = t0 + tl1;
  if (ta < T_DIM)
    *(f32x4*)&out[((size_t)b * T_DIM + ta) * ODIM + g4 * 4] = accA;
  if (tb < T_DIM)
    *(f32x4*)&out[((size_t)b * T_DIM + tb) * ODIM + g4 * 4] = accB;
}

extern "C" void kernel_launch(void* const* d_in, const int* in_sizes, int n_in,
                              void* d_out, int out_size, void* d_ws, size_t ws_size,
                              hipStream_t stream) {
  const int* frames = (const int*)d_in[0];     // (16,100,27,48,3) int32
  const float* fc_w = (const float*)d_in[1];   // (101,128) f32
  const float* fc_b = (const float*)d_in[2];   // (128,) f32
  float* out = (float*)d_out;                  // (16,100,128) f32
  __hip_bfloat16* X16 = (__hip_bfloat16*)d_ws; // 16*112*512 bf16 = 1.835 MB

  void* args[] = {(void*)&frames, (void*)&fc_w, (void*)&fc_b, (void*)&out,
                  (void*)&X16};
  hipLaunchCooperativeKernel((void*)fused_kernel, dim3(NBLOCKS), dim3(256),
                             args, 0, stream);
}

// Round 4
// 86.117 us; speedup vs baseline: 2.2715x; 2.2715x over previous
//
#include <hip/hip_runtime.h>
#include <hip/hip_bf16.h>
#include <math.h>

#define B_DIM 16
#define T_DIM 100
#define TPAD 112            // 7 MFMA row-tiles of 16
#define HW_PIX (27 * 48)    // 1296 pixels/frame
#define NBINS 512
#define WIN 101
#define HALF 50
#define ODIM 128
#define NTILE 7             // TPAD/16
#define SSTRIDE 132         // S-block row stride in LDS (132%32=4 -> only 2-way aliasing)
#define NFRAMES (B_DIM * T_DIM)

typedef __attribute__((ext_vector_type(8))) short s16x8;
typedef __attribute__((ext_vector_type(4))) float f32x4;

// ---------------------------------------------------------------------------
// Kernel A: one WAVE per frame (64-thread blocks), wave-private 512-bin LDS
// histogram -> no barriers, no cross-wave atomic contention, no cross-wave
// reduce. L2-normalized, packed-bf16 dword stores into X16[b][t][512].
// Blocks 1600..1615 zero row 100 of each batch (the clamp row for
// out-of-range band columns). Rows 101..111 stay poison (feed only
// discarded MFMA output rows).
// ---------------------------------------------------------------------------
__global__ __launch_bounds__(64) void hist_kernel(
    const int* __restrict__ frames, __hip_bfloat16* __restrict__ X16) {
  __shared__ int hw[NBINS];
  const int bid = blockIdx.x;
  const int lane = threadIdx.x;

  if (bid >= NFRAMES) {
    // zero row 100 of batch (bid-1600)
    const int b = bid - NFRAMES;
    unsigned int* zr = (unsigned int*)(X16 + ((size_t)(b * TPAD + T_DIM)) * NBINS);
#pragma unroll
    for (int k = 0; k < 4; ++k) zr[lane + 64 * k] = 0u;
    return;
  }

#pragma unroll
  for (int k = 0; k < 8; ++k) hw[lane + 64 * k] = 0;
  // single wave: program order suffices, no barrier

  // 324 groups of 4 pixels (12 dwords = 3 int4 loads each)
  const int* fp = frames + (size_t)bid * (HW_PIX * 3);
  for (int g = lane; g < HW_PIX / 4; g += 64) {
    const int4* q = (const int4*)(fp + 12 * g);
    int4 a = q[0], c = q[1], e = q[2];
    int b0 = ((a.x >> 5) << 6) + ((a.y >> 5) << 3) + (a.z >> 5);
    int b1 = ((a.w >> 5) << 6) + ((c.x >> 5) << 3) + (c.y >> 5);
    int b2 = ((c.z >> 5) << 6) + ((c.w >> 5) << 3) + (e.x >> 5);
    int b3 = ((e.y >> 5) << 6) + ((e.z >> 5) << 3) + (e.w >> 5);
    atomicAdd(&hw[b0], 1);
    atomicAdd(&hw[b1], 1);
    atomicAdd(&hw[b2], 1);
    atomicAdd(&hw[b3], 1);
  }

  // L2-norm: bins partitioned lane+64k (conflict-free), butterfly reduce
  float ss = 0.f;
#pragma unroll
  for (int k = 0; k < 8; ++k) {
    float v = (float)hw[lane + 64 * k];
    ss += v * v;
  }
#pragma unroll
  for (int off = 32; off > 0; off >>= 1) ss += __shfl_xor(ss, off);
  const float rn = 1.0f / sqrtf(ss);

  // packed bf16 store: dword i <- bins {2i, 2i+1}, i = lane + 64k
  const int b = bid / T_DIM;
  const int t = bid - b * T_DIM;
  unsigned int* row = (unsigned int*)(X16 + ((size_t)(b * TPAD + t)) * NBINS);
  const int2* h2 = (const int2*)hw;
#pragma unroll
  for (int k = 0; k < 4; ++k) {
    int i = lane + 64 * k;
    int2 p = h2[i];
    unsigned int lo = (unsigned int)__bfloat16_as_ushort(
        __float2bfloat16((float)p.x * rn));
    unsigned int hi = (unsigned int)__bfloat16_as_ushort(
        __float2bfloat16((float)p.y * rn));
    row[i] = lo | (hi << 16);
  }
}

// ---------------------------------------------------------------------------
// Kernel B (fused sim + band + FC):
// Grid = 16 batches * 7 chunks of 16 t's; 256 threads (4 waves).
// Phase 1: each wave computes 2 column-tiles of S[16][128] where
//   S[m][n] = dot(X[t0+m], X[t0-50+n])  via mfma_f32_16x16x32_bf16,
//   reading fragments straight from L2-resident X16 (no LDS staging).
//   Out-of-range rows (s<0 or s>=100) clamp to the zeroed row 100.
// Phase 2: band[tl][j] = S[tl][tl+j]; FC(101->128) + ReLU in f32.
// LDS: fc_w (101x128 f32, 51712 B) + S (16 x 132 f32, 8448 B) = 60160 B.
// ---------------------------------------------------------------------------
__global__ __launch_bounds__(256) void simfc_kernel(
    const __hip_bfloat16* __restrict__ X16, const float* __restrict__ fc_w,
    const float* __restrict__ fc_b, float* __restrict__ out) {
  __shared__ __align__(16) float wlds[WIN * ODIM];   // 51712 B
  __shared__ __align__(16) float slds[16 * SSTRIDE]; // 8448 B

  const int cid = blockIdx.x;
  const int b = cid / NTILE;
  const int t0 = (cid - b * NTILE) * 16;
  const int tid = threadIdx.x;

  // stage fc_w as float4 (consumed after the barrier; overlaps MFMA issue)
  {
    const f32x4* src = (const f32x4*)fc_w;
    f32x4* dst = (f32x4*)wlds;
    for (int i = tid; i < (WIN * ODIM) / 4; i += 256) dst[i] = src[i];
  }

  // ---- Phase 1: MFMA S-block ----
  const int lane = tid & 63, wv = tid >> 6;
  const int m16 = lane & 15, quad = lane >> 4;

  // A rows t0+m16 <= 111 < TPAD (pad rows 101..111 feed only discarded
  // outputs; row 100 is zeroed).
  const short* Abase =
      (const short*)(X16 + ((size_t)(b * TPAD + t0 + m16)) * NBINS) + quad * 8;
  const short* zrow =
      (const short*)(X16 + ((size_t)(b * TPAD + T_DIM)) * NBINS) + quad * 8;

  // wave wv owns columns n in [wv*32, wv*32+31] (two 16-wide n-tiles)
  const int s0 = t0 - HALF + wv * 32 + m16;
  const int s1 = s0 + 16;
  const short* B0 = (s0 >= 0 && s0 < T_DIM)
      ? (const short*)(X16 + ((size_t)(b * TPAD + s0)) * NBINS) + quad * 8
      : zrow;
  const short* B1 = (s1 >= 0 && s1 < T_DIM)
      ? (const short*)(X16 + ((size_t)(b * TPAD + s1)) * NBINS) + quad * 8
      : zrow;

  f32x4 acc0 = {0.f, 0.f, 0.f, 0.f};
  f32x4 acc1 = {0.f, 0.f, 0.f, 0.f};
#pragma unroll 8
  for (int k = 0; k < NBINS; k += 32) {
    s16x8 af = *(const s16x8*)(Abase + k);
    s16x8 bf0 = *(const s16x8*)(B0 + k);
    s16x8 bf1 = *(const s16x8*)(B1 + k);
    acc0 = __builtin_amdgcn_mfma_f32_16x16x32_bf16(af, bf0, acc0, 0, 0, 0);
    acc1 = __builtin_amdgcn_mfma_f32_16x16x32_bf16(af, bf1, acc1, 0, 0, 0);
  }

  // D layout: col = lane&15, row = quad*4 + r. Stride 132 -> 2-way max (free).
#pragma unroll
  for (int r = 0; r < 4; ++r) {
    slds[(quad * 4 + r) * SSTRIDE + wv * 32 + m16] = acc0[r];
    slds[(quad * 4 + r) * SSTRIDE + wv * 32 + 16 + m16] = acc1[r];
  }
  __syncthreads();

  // ---- Phase 2: FC. band[tl][j] = S[tl][tl+j] (max col 15+100=115 < 128) ----
  const int g4 = tid & 31;        // d = 4*g4 .. 4*g4+3
  const int tl0 = tid >> 5;       // 0..7
  const int tl1 = tl0 + 8;

  f32x4 accA = ((const f32x4*)fc_b)[g4];
  f32x4 accB = accA;
#pragma unroll 4
  for (int j = 0; j < WIN; ++j) {
    f32x4 w4 = *(const f32x4*)&wlds[j * ODIM + g4 * 4];
    float v0 = slds[tl0 * SSTRIDE + tl0 + j];
    float v1 = slds[tl1 * SSTRIDE + tl1 + j];
    accA += w4 * v0;
    accB += w4 * v1;
  }

#pragma unroll
  for (int c = 0; c < 4; ++c) {
    accA[c] = fmaxf(accA[c], 0.f);
    accB[c] = fmaxf(accB[c], 0.f);
  }

  const int ta = t0 + tl0, tb = t0 + tl1;
  if (ta < T_DIM)
    *(f32x4*)&out[((size_t)b * T_DIM + ta) * ODIM + g4 * 4] = accA;
  if (tb < T_DIM)
    *(f32x4*)&out[((size_t)b * T_DIM + tb) * ODIM + g4 * 4] = accB;
}

extern "C" void kernel_launch(void* const* d_in, const int* in_sizes, int n_in,
                              void* d_out, int out_size, void* d_ws, size_t ws_size,
                              hipStream_t stream) {
  const int* frames = (const int*)d_in[0];     // (16,100,27,48,3) int32
  const float* fc_w = (const float*)d_in[1];   // (101,128) f32
  const float* fc_b = (const float*)d_in[2];   // (128,) f32
  float* out = (float*)d_out;                  // (16,100,128) f32

  __hip_bfloat16* X16 = (__hip_bfloat16*)d_ws; // 16*112*512 bf16 = 1.835 MB

  hist_kernel<<<NFRAMES + B_DIM, 64, 0, stream>>>(frames, X16);
  simfc_kernel<<<B_DIM * NTILE, 256, 0, stream>>>(X16, fc_w, fc_b, out);
}